// Round 5
// baseline (361.806 us; speedup 1.0000x reference)
//
#include <hip/hip_runtime.h>
#include <hip/hip_bf16.h>
#include <cstdint>

#define KDIM 1024
#define BDIM 8192
#define VDIM 2
#define NBLK 16  // KDIM / 64

typedef __attribute__((ext_vector_type(8))) short short8;
typedef __attribute__((ext_vector_type(4))) float f32x4;

__device__ inline unsigned short f2bf(float x) {
  unsigned u = __builtin_bit_cast(unsigned, x);
  u = (u + 0x7FFFu + ((u >> 16) & 1u)) >> 16;
  return (unsigned short)u;
}

__device__ inline float bf2f(unsigned short x) {
  return __builtin_bit_cast(float, (unsigned)x << 16);
}

// ---------------------------------------------------------------------------
// Workspace layout (bytes from d_ws):
//   MT   @ 0        4 MB fp32   M^T (MT[t][i] = M[i][t])
//   Mbf  @ 4 MB     2 MB bf16   M row-major (Mbf[i][k] = M[i][k])
//   Pt2  @ 6 MB     0.5 MB      lv2 P scratch
//   Pt3  @ 6.5 MB   1 MB        lv3 P scratch
//   Zbf  @ 7.5 MB   16 MB       Z in bf16
// ---------------------------------------------------------------------------

// ----------------- 64-wide tile helpers (comb01 only, verified) ------------
#define STAGE_T(DST, SRC, ROW0, COL0, LD)                                   \
  {                                                                         \
    const float* _s = (SRC);                                                \
    _Pragma("unroll") for (int _p = 0; _p < 4; ++_p) {                      \
      const int _m = _p * 16 + rw;                                          \
      float4 _v = *(const float4*)(_s + (size_t)((ROW0) + _m) * (LD) +      \
                                   (COL0) + 4 * k4);                        \
      (DST)[4 * k4 + 0][_m] = _v.x;                                         \
      (DST)[4 * k4 + 1][_m] = _v.y;                                         \
      (DST)[4 * k4 + 2][_m] = _v.z;                                         \
      (DST)[4 * k4 + 3][_m] = _v.w;                                         \
    }                                                                       \
  }

#define STAGE_D(DST, SRC, ROW0, COL0, LD)                                   \
  {                                                                         \
    const float* _s = (SRC);                                                \
    _Pragma("unroll") for (int _p = 0; _p < 4; ++_p) {                      \
      const int _kk = _p * 16 + rw;                                         \
      *(float4*)&(DST)[_kk][4 * k4] =                                       \
          *(const float4*)(_s + (size_t)((ROW0) + _kk) * (LD) + (COL0) +    \
                           4 * k4);                                         \
    }                                                                       \
  }

#define ZERO_ACC                                                            \
  _Pragma("unroll") for (int _a = 0; _a < 4; ++_a)                          \
      _Pragma("unroll") for (int _b = 0; _b < 4; ++_b) acc[_a][_b] = 0.f;

__device__ __forceinline__ void mac64(const float (*Ls)[68],
                                      const float (*Rs)[68], int tm, int tn,
                                      float acc[4][4]) {
#pragma unroll 4
  for (int k = 0; k < 64; ++k) {
    const float4 av = *(const float4*)&Ls[k][4 * tm];
    const float4 bv = *(const float4*)&Rs[k][4 * tn];
    const float aa[4] = {av.x, av.y, av.z, av.w};
    const float bb4[4] = {bv.x, bv.y, bv.z, bv.w};
#pragma unroll
    for (int a = 0; a < 4; ++a)
#pragma unroll
      for (int b = 0; b < 4; ++b) acc[a][b] += aa[a] * bb4[b];
  }
}

#define STORE_MT(R0, C0)                                                    \
  _Pragma("unroll") for (int _a = 0; _a < 4; ++_a) {                        \
    *(float4*)(MT + (size_t)((R0) + 4 * tm + _a) * KDIM + (C0) + 4 * tn) =  \
        make_float4(acc[_a][0], acc[_a][1], acc[_a][2], acc[_a][3]);        \
  }

#define MBF_TILE(R0, C0, BUF)                                               \
  {                                                                         \
    __syncthreads();                                                        \
    _Pragma("unroll") for (int _a = 0; _a < 4; ++_a)                        \
        _Pragma("unroll") for (int _b = 0; _b < 4; ++_b)                    \
            (BUF)[4 * tm + _a][4 * tn + _b] = acc[_a][_b];                  \
    __syncthreads();                                                        \
    const int _tr = tid >> 4, _tc = tid & 15;                               \
    _Pragma("unroll") for (int _p = 0; _p < 4; ++_p) {                      \
      const int _il = _p * 16 + _tr;                                        \
      ushort4 _o;                                                           \
      _o.x = f2bf((BUF)[4 * _tc + 0][_il]);                                 \
      _o.y = f2bf((BUF)[4 * _tc + 1][_il]);                                 \
      _o.z = f2bf((BUF)[4 * _tc + 2][_il]);                                 \
      _o.w = f2bf((BUF)[4 * _tc + 3][_il]);                                 \
      *(ushort4*)(Mbf + (size_t)((C0) + _il) * KDIM + (R0) + 4 * _tc) = _o; \
    }                                                                       \
  }

// ----------------- 32-wide tile helpers (lv2/lv3 kernels) -------------------
// Ls/Rs are [64][37].  Output tile is 32x32, 2x2 micro per thread (256 thr).
// STAGE_T32: DST[k][m] = SRC[(ROW0+m)*LD + COL0 + k], m<32, k<64
#define STAGE_T32(DST, SRC, ROW0, COL0, LD)                                 \
  {                                                                         \
    const float* _s = (SRC);                                                \
    _Pragma("unroll") for (int _p = 0; _p < 2; ++_p) {                      \
      const int _m = _p * 16 + (tid >> 4);                                  \
      const int _k4 = tid & 15;                                             \
      float4 _v = *(const float4*)(_s + (size_t)((ROW0) + _m) * (LD) +      \
                                   (COL0) + 4 * _k4);                       \
      (DST)[4 * _k4 + 0][_m] = _v.x;                                        \
      (DST)[4 * _k4 + 1][_m] = _v.y;                                        \
      (DST)[4 * _k4 + 2][_m] = _v.z;                                        \
      (DST)[4 * _k4 + 3][_m] = _v.w;                                        \
    }                                                                       \
  }

// STAGE_D32: DST[kk][n] = SRC[(ROW0+kk)*LD + COL0 + n], kk<64, n<32
#define STAGE_D32(DST, SRC, ROW0, COL0, LD)                                 \
  {                                                                         \
    const float* _s = (SRC);                                                \
    _Pragma("unroll") for (int _p = 0; _p < 2; ++_p) {                      \
      const int _kk = _p * 32 + (tid >> 3);                                 \
      const int _k8 = tid & 7;                                              \
      *(float4*)&(DST)[_kk][4 * _k8] =                                      \
          *(const float4*)(_s + (size_t)((ROW0) + _kk) * (LD) + (COL0) +    \
                           4 * _k8);                                        \
    }                                                                       \
  }

__device__ __forceinline__ void mac32(const float (*Ls)[37],
                                      const float (*Rs)[37], int tm, int tn,
                                      float acc[2][2]) {
#pragma unroll 8
  for (int k = 0; k < 64; ++k) {
    const float2 av = *(const float2*)&Ls[k][2 * tm];
    const float2 bv = *(const float2*)&Rs[k][2 * tn];
    acc[0][0] += av.x * bv.x;
    acc[0][1] += av.x * bv.y;
    acc[1][0] += av.y * bv.x;
    acc[1][1] += av.y * bv.y;
  }
}

// ---------------------------------------------------------------------------
// prep_inv: invert the 16 diagonal 64x64 unit-lower-tri blocks of (I - A).
// ---------------------------------------------------------------------------
__global__ __launch_bounds__(256) void prep_inv(const float* __restrict__ A,
                                                float* __restrict__ MT,
                                                unsigned short* __restrict__ Mbf) {
  __shared__ float As[64 * 64];
  const int base = blockIdx.x * 64;
  for (int i = threadIdx.x; i < 64 * 64; i += 256)
    As[i] = A[(size_t)(base + (i >> 6)) * KDIM + base + (i & 63)];
  __syncthreads();
  if (threadIdx.x < 64) {
    const int c = threadIdx.x;
    float m[64];
#pragma unroll
    for (int r = 0; r < 64; ++r) m[r] = (r == c) ? 1.f : 0.f;
#pragma unroll
    for (int r = 1; r < 64; ++r) {
      float acc0 = 0.f, acc1 = 0.f;
#pragma unroll
      for (int i = 0; i < 64; ++i) {
        if (i >= r) break;
        if (i & 1) acc1 += As[r * 64 + i] * m[i];
        else       acc0 += As[r * 64 + i] * m[i];
      }
      const float v = acc0 + acc1;
      m[r] = (r > c) ? v : m[r];
    }
#pragma unroll
    for (int r = 0; r < 64; r += 4) {
      float4 v = make_float4(m[r], m[r + 1], m[r + 2], m[r + 3]);
      *(float4*)(MT + (size_t)(base + c) * KDIM + base + r) = v;
    }
#pragma unroll
    for (int r = 0; r < 64; ++r)
      Mbf[(size_t)(base + r) * KDIM + base + c] = f2bf(m[r]);
  }
}

// ---------------------------------------------------------------------------
// comb01: merged levels h=64 and h=128 (verified, unchanged).
// ---------------------------------------------------------------------------
__global__ __launch_bounds__(256) void comb01(const float* __restrict__ A,
                                              float* __restrict__ MT,
                                              unsigned short* __restrict__ Mbf) {
  int b = blockIdx.x;
  const int rt = b & 1;
  const int jt = (b >> 1) & 1;
  const int s = b >> 2;
  const int base = s * 256;

  __shared__ float Ls[64][68];
  __shared__ float Rs[64][68];
  __shared__ float tQ0L[64][68];
  __shared__ float tQ0H[64][68];
  __shared__ float tP0[64][68];
  __shared__ float tP1[64][68];

  const int tid = threadIdx.x;
  const int k4 = tid & 15;
  const int rw = tid >> 4;
  const int tm = tid >> 4;
  const int tn = tid & 15;
  float acc[4][4];

  if (jt == 0) {
    STAGE_T(Ls, MT, base, base, KDIM);
    STAGE_T(Rs, A, base + 64, base, KDIM);
    __syncthreads();
    ZERO_ACC;
    mac64(Ls, Rs, tm, tn, acc);
    __syncthreads();
#pragma unroll
    for (int a = 0; a < 4; ++a)
#pragma unroll
      for (int b2 = 0; b2 < 4; ++b2) tP0[4 * tn + b2][4 * tm + a] = acc[a][b2];
    STAGE_D(Rs, MT, base + 64, base + 64, KDIM);
    __syncthreads();
    ZERO_ACC;
    mac64(tP0, Rs, tm, tn, acc);
    __syncthreads();
#pragma unroll
    for (int a = 0; a < 4; ++a)
#pragma unroll
      for (int b2 = 0; b2 < 4; ++b2) tQ0L[4 * tn + b2][4 * tm + a] = acc[a][b2];
    if (rt == 0) {
      STORE_MT(base, base + 64);
      MBF_TILE(base, base + 64, Rs);
    }
  }
  __syncthreads();

  if (rt == 1) {
    STAGE_T(Ls, MT, base + 128, base + 128, KDIM);
    STAGE_T(Rs, A, base + 192, base + 128, KDIM);
    __syncthreads();
    ZERO_ACC;
    mac64(Ls, Rs, tm, tn, acc);
    __syncthreads();
#pragma unroll
    for (int a = 0; a < 4; ++a)
#pragma unroll
      for (int b2 = 0; b2 < 4; ++b2) tP1[4 * tn + b2][4 * tm + a] = acc[a][b2];
    STAGE_D(Rs, MT, base + 192, base + 192, KDIM);
    __syncthreads();
    ZERO_ACC;
    mac64(tP1, Rs, tm, tn, acc);
    __syncthreads();
#pragma unroll
    for (int a = 0; a < 4; ++a)
#pragma unroll
      for (int b2 = 0; b2 < 4; ++b2) tQ0H[4 * tm + a][4 * tn + b2] = acc[a][b2];
    if (jt == 1) {
      STORE_MT(base + 128, base + 192);
      MBF_TILE(base + 128, base + 192, Rs);
    }
  }
  __syncthreads();

  STAGE_T(Ls, MT, base + 64 * jt, base + 64 * jt, KDIM);
  __syncthreads();
  for (int kb2 = 0; kb2 <= rt; ++kb2) {
    ZERO_ACC;
    for (int kb = jt; kb < 2; ++kb) {
      STAGE_T(Rs, A, base + 128 + 64 * kb2, base + 64 * kb, KDIM);
      __syncthreads();
      mac64(kb == jt ? Ls : tQ0L, Rs, tm, tn, acc);
      __syncthreads();
    }
    if (kb2 == 0) {
#pragma unroll
      for (int a = 0; a < 4; ++a)
#pragma unroll
        for (int b2 = 0; b2 < 4; ++b2) tP0[4 * tn + b2][4 * tm + a] = acc[a][b2];
    } else {
#pragma unroll
      for (int a = 0; a < 4; ++a)
#pragma unroll
        for (int b2 = 0; b2 < 4; ++b2) tP1[4 * tn + b2][4 * tm + a] = acc[a][b2];
    }
  }
  __syncthreads();

  ZERO_ACC;
  if (rt == 0) {
    STAGE_D(Rs, MT, base + 128, base + 128, KDIM);
    __syncthreads();
    mac64(tP0, Rs, tm, tn, acc);
    __syncthreads();
  } else {
    mac64(tP0, tQ0H, tm, tn, acc);
    __syncthreads();
    STAGE_D(Rs, MT, base + 192, base + 192, KDIM);
    __syncthreads();
    mac64(tP1, Rs, tm, tn, acc);
    __syncthreads();
  }
  STORE_MT(base + 64 * jt, base + 128 + 64 * rt);
  MBF_TILE(base + 64 * jt, base + 128 + 64 * rt, Rs);
}

// ---------------------------------------------------------------------------
// p4_stream: blocks 0..127 compute lv2 P tiles at 32x32 (c, j32<8, r32<8);
// blocks 128+ do streaming: zero MT strict-lower / Mbf strict-upper blocks,
// convert Z -> bf16.
// ---------------------------------------------------------------------------
__global__ __launch_bounds__(256) void p4_stream(
    const float* __restrict__ A, float* __restrict__ MT,
    float* __restrict__ Pt, const float* __restrict__ Z,
    unsigned short* __restrict__ Zbf, unsigned short* __restrict__ Mbf,
    int do_zbf) {
  __shared__ float Ls[64][37];
  __shared__ float Rs[64][37];

  if (blockIdx.x >= 128) {
    const int wid = blockIdx.x - 128;
    const int nw = gridDim.x - 128;
    const int idx0 = wid * 256 + threadIdx.x;
    const int stride = nw * 256;
    const float4 z4 = make_float4(0.f, 0.f, 0.f, 0.f);
    const uint4 u4 = make_uint4(0u, 0u, 0u, 0u);

    for (int i = idx0; i < 256 * 1024; i += stride) {
      const int blk = i >> 10, off = i & 1023;
      const int bi = blk >> 4, bj = blk & 15;
      if (bi <= bj) continue;  // strict-lower MT blocks only
      *(float4*)(MT + (size_t)(bi * 64 + (off >> 4)) * KDIM + bj * 64 +
                 4 * (off & 15)) = z4;
    }
    for (int i = idx0; i < 256 * 512; i += stride) {
      const int blk = i >> 9, off = i & 511;
      const int bi = blk >> 4, bj = blk & 15;
      if (bi >= bj) continue;  // strict-upper Mbf blocks only
      *(uint4*)(Mbf + (size_t)(bi * 64 + (off >> 3)) * KDIM + bj * 64 +
                8 * (off & 7)) = u4;
    }
    if (do_zbf) {
      for (int i = idx0; i < BDIM * KDIM / 4; i += stride) {
        float4 v = *(const float4*)(Z + 4 * (size_t)i);
        ushort4 o;
        o.x = f2bf(v.x);
        o.y = f2bf(v.y);
        o.z = f2bf(v.z);
        o.w = f2bf(v.w);
        *(ushort4*)(Zbf + 4 * (size_t)i) = o;
      }
    }
    return;
  }

  // ---- lv2 P tiles, 32x32 (T=4, h=256) ----
  int b = blockIdx.x;
  const int r32 = b & 7;
  const int j32 = (b >> 3) & 7;
  const int c = b >> 6;
  const int h = 256;
  const int base = c * 512;

  const int tid = threadIdx.x;
  const int tm = tid >> 4;
  const int tn = tid & 15;
  float acc[2][2] = {{0.f, 0.f}, {0.f, 0.f}};

  for (int kb = (j32 >> 1); kb < 4; ++kb) {
    STAGE_T32(Ls, MT, base + 32 * j32, base + 64 * kb, KDIM);
    STAGE_T32(Rs, A, base + h + 32 * r32, base + 64 * kb, KDIM);
    __syncthreads();
    mac32(Ls, Rs, tm, tn, acc);
    __syncthreads();
  }

  float* P0 = Pt + (size_t)c * h * h;
#pragma unroll
  for (int a = 0; a < 2; ++a)
    *(float2*)(P0 + (size_t)(32 * j32 + 2 * tm + a) * h + 32 * r32 + 2 * tn) =
        make_float2(acc[a][0], acc[a][1]);
}

// ---------------------------------------------------------------------------
// p_k32<T>: lv P tiles at 32x32.  grid = combines * (2T)^2.
// ---------------------------------------------------------------------------
template <int T>
__global__ __launch_bounds__(256) void p_k32(const float* __restrict__ A,
                                             const float* __restrict__ MT,
                                             float* __restrict__ Pt) {
  __shared__ float Ls[64][37];
  __shared__ float Rs[64][37];

  int b = blockIdx.x;
  const int r32 = b & (2 * T - 1);
  b >>= (T == 4 ? 3 : 4);
  const int j32 = b & (2 * T - 1);
  b >>= (T == 4 ? 3 : 4);
  const int c = b;
  const int h = 64 * T;
  const int base = c * 2 * h;

  const int tid = threadIdx.x;
  const int tm = tid >> 4;
  const int tn = tid & 15;
  float acc[2][2] = {{0.f, 0.f}, {0.f, 0.f}};

  for (int kb = (j32 >> 1); kb < T; ++kb) {
    STAGE_T32(Ls, MT, base + 32 * j32, base + 64 * kb, KDIM);
    STAGE_T32(Rs, A, base + h + 32 * r32, base + 64 * kb, KDIM);
    __syncthreads();
    mac32(Ls, Rs, tm, tn, acc);
    __syncthreads();
  }

  float* P0 = Pt + (size_t)c * h * h;
#pragma unroll
  for (int a = 0; a < 2; ++a)
    *(float2*)(P0 + (size_t)(32 * j32 + 2 * tm + a) * h + 32 * r32 + 2 * tn) =
        make_float2(acc[a][0], acc[a][1]);
}

// ---------------------------------------------------------------------------
// q_k32<T>: Q tiles at 32x32; writes final MT tile + bf16 Mbf mirror.
// ---------------------------------------------------------------------------
template <int T>
__global__ __launch_bounds__(256) void q_k32(float* __restrict__ MT,
                                             const float* __restrict__ Pt,
                                             unsigned short* __restrict__ Mbf) {
  __shared__ float Ls[64][37];
  __shared__ float Rs[64][37];

  int b = blockIdx.x;
  const int r32 = b & (2 * T - 1);
  b >>= (T == 4 ? 3 : 4);
  const int j32 = b & (2 * T - 1);
  b >>= (T == 4 ? 3 : 4);
  const int c = b;
  const int h = 64 * T;
  const int base = c * 2 * h;

  const int tid = threadIdx.x;
  const int tm = tid >> 4;
  const int tn = tid & 15;
  float acc[2][2] = {{0.f, 0.f}, {0.f, 0.f}};

  const float* P0 = Pt + (size_t)c * h * h;
  for (int kb = 0; kb <= (r32 >> 1); ++kb) {
    STAGE_T32(Ls, P0, 32 * j32, 64 * kb, h);
    STAGE_D32(Rs, MT, base + h + 64 * kb, base + h + 32 * r32, KDIM);
    __syncthreads();
    mac32(Ls, Rs, tm, tn, acc);
    __syncthreads();
  }

  const int R0 = base + 32 * j32;
  const int C0 = base + h + 32 * r32;
#pragma unroll
  for (int a = 0; a < 2; ++a)
    *(float2*)(MT + (size_t)(R0 + 2 * tm + a) * KDIM + C0 + 2 * tn) =
        make_float2(acc[a][0], acc[a][1]);

  // bf16 mirror: Mbf[C0+il][R0+j] = tile[j][il], bounce through Ls.
  float (*BUF)[37] = Ls;
  __syncthreads();
#pragma unroll
  for (int a = 0; a < 2; ++a)
#pragma unroll
    for (int b2 = 0; b2 < 2; ++b2)
      BUF[2 * tm + a][2 * tn + b2] = acc[a][b2];
  __syncthreads();
  {
    const int il = tid >> 3;        // 0..31
    const int tc = tid & 7;         // 0..7 (x4 cols)
    ushort4 o;
    o.x = f2bf(BUF[4 * tc + 0][il]);
    o.y = f2bf(BUF[4 * tc + 1][il]);
    o.z = f2bf(BUF[4 * tc + 2][il]);
    o.w = f2bf(BUF[4 * tc + 3][il]);
    *(ushort4*)(Mbf + (size_t)(C0 + il) * KDIM + R0 + 4 * tc) = o;
  }
}

// ---------------------------------------------------------------------------
// bf16 MFMA GEMM with fused per-sample correction (verified round 4).
// ---------------------------------------------------------------------------
#define LDB 72

template <int ZBF>
__global__ __launch_bounds__(256) void gemm_mfma(
    const float* __restrict__ Z, const unsigned short* __restrict__ Zbf,
    const unsigned short* __restrict__ Mbf, const float* __restrict__ MT,
    const int* __restrict__ tgt, const int* __restrict__ var,
    const float* __restrict__ means, const float* __restrict__ lsc,
    float* __restrict__ C) {
  __shared__ unsigned short As[128][LDB];
  __shared__ unsigned short Bs[128][LDB];
  __shared__ float scoef[128];
  __shared__ int stb[128];

  const int d = blockIdx.x;
  const int xbl = d & 7;
  const int nir = (d >> 3) & 7;
  const int xbh = d >> 6;
  const int xb = xbh * 8 + xbl;
  const int ni = (xb & 32) ? (7 - nir) : nir;
  const int b0 = xb * 128;
  const int i0 = ni * 128;

  const int tid = threadIdx.x;
  const int w = tid >> 6;
  const int lane = tid & 63;
  const int wr = w >> 1, wc = w & 1;
  const int mlane = lane & 15;
  const int q = lane >> 4;

  const int rq = tid >> 4, kq = tid & 15;
  const int cb = tid >> 3, ck = tid & 7;

  f32x4 acc[4][4];
#pragma unroll
  for (int a = 0; a < 4; ++a)
#pragma unroll
    for (int b = 0; b < 4; ++b) acc[a][b] = (f32x4){0.f, 0.f, 0.f, 0.f};

  const int nkb = 2 * (ni + 1);
  for (int kb = 0; kb < nkb; ++kb) {
    const int k0 = kb * 64;
    if (ZBF) {
#pragma unroll
      for (int p = 0; p < 4; ++p) {
        const int r = p * 32 + cb;
        *(uint4*)&As[r][8 * ck] =
            *(const uint4*)(Zbf + (size_t)(b0 + r) * KDIM + k0 + 8 * ck);
      }
    } else {
#pragma unroll
      for (int p = 0; p < 8; ++p) {
        const int r = p * 16 + rq;
        float4 zv = *(const float4*)(Z + (size_t)(b0 + r) * KDIM + k0 + 4 * kq);
        ushort4 o;
        o.x = f2bf(zv.x);
        o.y = f2bf(zv.y);
        o.z = f2bf(zv.z);
        o.w = f2bf(zv.w);
        *(ushort4*)&As[r][4 * kq] = o;
      }
    }
#pragma unroll
    for (int p = 0; p < 4; ++p) {
      const int c = p * 32 + cb;
      *(uint4*)&Bs[c][8 * ck] =
          *(const uint4*)(Mbf + (size_t)(i0 + c) * KDIM + k0 + 8 * ck);
    }
    __syncthreads();
#pragma unroll
    for (int ks = 0; ks < 2; ++ks) {
      const int kf = ks * 32 + q * 8;
      short8 av[4], bv[4];
#pragma unroll
      for (int a = 0; a < 4; ++a)
        av[a] = *(const short8*)&As[wr * 64 + 16 * a + mlane][kf];
#pragma unroll
      for (int b = 0; b < 4; ++b)
        bv[b] = *(const short8*)&Bs[wc * 64 + 16 * b + mlane][kf];
#pragma unroll
      for (int a = 0; a < 4; ++a)
#pragma unroll
        for (int b = 0; b < 4; ++b)
          acc[a][b] =
              __builtin_amdgcn_mfma_f32_16x16x32_bf16(av[a], bv[b], acc[a][b], 0, 0, 0);
    }
    __syncthreads();
  }

  // ---- fused correction: coef for this block's 128 samples ----
  {
    const int s = tid >> 1, h2 = tid & 1;  // 2 threads per sample
    const int br = b0 + s;
    const int tb = tgt[br];
    float part = 0.f;
    if (tb >= 0) {
      const int nk16 = (tb >> 4) + 1;
      if (ZBF) {
        const unsigned short* zr = Zbf + (size_t)br * KDIM;
        const unsigned short* mr = Mbf + (size_t)tb * KDIM;
        for (int c16 = h2; c16 < nk16; c16 += 2) {
          const uint4 za = *(const uint4*)(zr + c16 * 16);
          const uint4 zb2 = *(const uint4*)(zr + c16 * 16 + 8);
          const uint4 ma = *(const uint4*)(mr + c16 * 16);
          const uint4 mb2 = *(const uint4*)(mr + c16 * 16 + 8);
          const unsigned zw[8] = {za.x, za.y, za.z, za.w,
                                  zb2.x, zb2.y, zb2.z, zb2.w};
          const unsigned mw[8] = {ma.x, ma.y, ma.z, ma.w,
                                  mb2.x, mb2.y, mb2.z, mb2.w};
#pragma unroll
          for (int wv = 0; wv < 8; ++wv) {
            part += __builtin_bit_cast(float, zw[wv] << 16) *
                    __builtin_bit_cast(float, mw[wv] << 16);
            part += __builtin_bit_cast(float, zw[wv] & 0xFFFF0000u) *
                    __builtin_bit_cast(float, mw[wv] & 0xFFFF0000u);
          }
        }
      } else {
        const float* zr = Z + (size_t)br * KDIM;
        const unsigned short* mr = Mbf + (size_t)tb * KDIM;
        const int nk8 = (tb >> 3) + 1;
        for (int c8 = h2; c8 < nk8; c8 += 2) {
          const float4 z0 = *(const float4*)(zr + c8 * 8);
          const float4 z1 = *(const float4*)(zr + c8 * 8 + 4);
          const ushort4 m0 = *(const ushort4*)(mr + c8 * 8);
          const ushort4 m1 = *(const ushort4*)(mr + c8 * 8 + 4);
          part += z0.x * bf2f(m0.x) + z0.y * bf2f(m0.y) + z0.z * bf2f(m0.z) +
                  z0.w * bf2f(m0.w) + z1.x * bf2f(m1.x) + z1.y * bf2f(m1.y) +
                  z1.z * bf2f(m1.z) + z1.w * bf2f(m1.w);
        }
      }
    }
    part += __shfl_down(part, 1);
    if (h2 == 0) {
      float cf = 0.f;
      int tbs = 0;
      if (tb >= 0) {
        const int v = var[br];
        const float mval = means[tb * VDIM + v];
        const float sval = expf(lsc[tb * VDIM + v]);
        const float zv = Z[(size_t)br * KDIM + tb];
        cf = (mval + sval * zv) - part;
        tbs = tb;
      }
      scoef[s] = cf;
      stb[s] = tbs;
    }
  }
  __syncthreads();

#pragma unroll
  for (int a = 0; a < 4; ++a) {
    const int l0 = wr * 64 + 16 * a + q * 4;
    const int row0 = b0 + l0;
#pragma unroll
    for (int b = 0; b < 4; ++b) {
      const int col = i0 + wc * 64 + 16 * b + mlane;
      float* Cp = C + (size_t)row0 * KDIM + col;
#pragma unroll
      for (int j = 0; j < 4; ++j) {
        const float cf = scoef[l0 + j];
        const float corr = cf * MT[(size_t)stb[l0 + j] * KDIM + col];
        Cp[j * KDIM] = acc[a][b][j] + corr;
      }
    }
  }
}

// ---------------------------------------------------------------------------
extern "C" void kernel_launch(void* const* d_in, const int* in_sizes, int n_in,
                              void* d_out, int out_size, void* d_ws,
                              size_t ws_size, hipStream_t stream) {
  const float* z = (const float*)d_in[0];
  const int* tgt = (const int*)d_in[1];
  const int* var = (const int*)d_in[2];
  const float* A = (const float*)d_in[3];
  const float* means = (const float*)d_in[4];
  const float* lsc = (const float*)d_in[5];
  float* out = (float*)d_out;

  char* ws = (char*)d_ws;
  float* MT = (float*)ws;                                    // 4 MB
  unsigned short* Mbf = (unsigned short*)(ws + (4u << 20));  // 2 MB
  float* Pt2 = (float*)(ws + (6u << 20));                    // 0.5 MB
  float* Pt3 = (float*)(ws + (6u << 20) + (512u << 10));     // 1 MB
  unsigned short* Zbf = (unsigned short*)(ws + (7u << 20) + (512u << 10));
  const int use_zbf =
      ws_size >= (7u << 20) + (512u << 10) + (size_t)BDIM * KDIM * 2 ? 1 : 0;

  hipLaunchKernelGGL(prep_inv, dim3(NBLK), dim3(256), 0, stream, A, MT, Mbf);
  hipLaunchKernelGGL(comb01, dim3(16), dim3(256), 0, stream, A, MT, Mbf);
  hipLaunchKernelGGL(p4_stream, dim3(512), dim3(256), 0, stream, A, MT, Pt2, z,
                     Zbf, Mbf, use_zbf);
  hipLaunchKernelGGL((q_k32<4>), dim3(128), dim3(256), 0, stream, MT, Pt2, Mbf);
  hipLaunchKernelGGL((p_k32<8>), dim3(256), dim3(256), 0, stream, A, MT, Pt3);
  hipLaunchKernelGGL((q_k32<8>), dim3(256), dim3(256), 0, stream, MT, Pt3, Mbf);
  if (use_zbf)
    hipLaunchKernelGGL((gemm_mfma<1>), dim3((BDIM / 128) * (KDIM / 128)),
                       dim3(256), 0, stream, z, Zbf, Mbf, MT, tgt, var, means,
                       lsc, out);
  else
    hipLaunchKernelGGL((gemm_mfma<0>), dim3((BDIM / 128) * (KDIM / 128)),
                       dim3(256), 0, stream, z, Zbf, Mbf, MT, tgt, var, means,
                       lsc, out);
}

// Round 6
// 244.129 us; speedup vs baseline: 1.4820x; 1.4820x over previous
//
#include <hip/hip_runtime.h>
#include <hip/hip_bf16.h>
#include <cstdint>

#define KDIM 1024
#define BDIM 8192
#define VDIM 2
#define NBLK 16  // KDIM / 64

#if defined(__has_builtin)
#if __has_builtin(__builtin_amdgcn_global_load_lds)
#define HAS_GLL 1
#endif
#endif
#ifndef HAS_GLL
#define HAS_GLL 0
#endif

typedef __attribute__((ext_vector_type(8))) short short8;
typedef __attribute__((ext_vector_type(4))) float f32x4;

__device__ inline unsigned short f2bf(float x) {
  unsigned u = __builtin_bit_cast(unsigned, x);
  u = (u + 0x7FFFu + ((u >> 16) & 1u)) >> 16;
  return (unsigned short)u;
}

__device__ inline float bf2f(unsigned short x) {
  return __builtin_bit_cast(float, (unsigned)x << 16);
}

// ---------------------------------------------------------------------------
// Workspace layout (bytes from d_ws):
//   MT   @ 0        4 MB fp32   M^T (MT[t][i] = M[i][t])
//   Mbf  @ 4 MB     2 MB bf16   M row-major (Mbf[i][k] = M[i][k])
//   Pt2  @ 6 MB     0.5 MB      lv2 P scratch
//   Pt3  @ 6.5 MB   1 MB        lv3 P scratch
//   Zbf  @ 7.5 MB   16 MB       Z in bf16
// ---------------------------------------------------------------------------

// --------------------------- shared tile helpers ---------------------------
#define STAGE_T(DST, SRC, ROW0, COL0, LD)                                   \
  {                                                                         \
    const float* _s = (SRC);                                                \
    _Pragma("unroll") for (int _p = 0; _p < 4; ++_p) {                      \
      const int _m = _p * 16 + rw;                                          \
      float4 _v = *(const float4*)(_s + (size_t)((ROW0) + _m) * (LD) +      \
                                   (COL0) + 4 * k4);                        \
      (DST)[4 * k4 + 0][_m] = _v.x;                                         \
      (DST)[4 * k4 + 1][_m] = _v.y;                                         \
      (DST)[4 * k4 + 2][_m] = _v.z;                                         \
      (DST)[4 * k4 + 3][_m] = _v.w;                                         \
    }                                                                       \
  }

#define STAGE_D(DST, SRC, ROW0, COL0, LD)                                   \
  {                                                                         \
    const float* _s = (SRC);                                                \
    _Pragma("unroll") for (int _p = 0; _p < 4; ++_p) {                      \
      const int _kk = _p * 16 + rw;                                         \
      *(float4*)&(DST)[_kk][4 * k4] =                                       \
          *(const float4*)(_s + (size_t)((ROW0) + _kk) * (LD) + (COL0) +    \
                           4 * k4);                                         \
    }                                                                       \
  }

#define ZERO_ACC                                                            \
  _Pragma("unroll") for (int _a = 0; _a < 4; ++_a)                          \
      _Pragma("unroll") for (int _b = 0; _b < 4; ++_b) acc[_a][_b] = 0.f;

__device__ __forceinline__ void mac64(const float (*Ls)[68],
                                      const float (*Rs)[68], int tm, int tn,
                                      float acc[4][4]) {
#pragma unroll 4
  for (int k = 0; k < 64; ++k) {
    const float4 av = *(const float4*)&Ls[k][4 * tm];
    const float4 bv = *(const float4*)&Rs[k][4 * tn];
    const float aa[4] = {av.x, av.y, av.z, av.w};
    const float bb4[4] = {bv.x, bv.y, bv.z, bv.w};
#pragma unroll
    for (int a = 0; a < 4; ++a)
#pragma unroll
      for (int b = 0; b < 4; ++b) acc[a][b] += aa[a] * bb4[b];
  }
}

#define STORE_MT(R0, C0)                                                    \
  _Pragma("unroll") for (int _a = 0; _a < 4; ++_a) {                        \
    *(float4*)(MT + (size_t)((R0) + 4 * tm + _a) * KDIM + (C0) + 4 * tn) =  \
        make_float4(acc[_a][0], acc[_a][1], acc[_a][2], acc[_a][3]);        \
  }

#define MBF_TILE(R0, C0, BUF)                                               \
  {                                                                         \
    __syncthreads();                                                        \
    _Pragma("unroll") for (int _a = 0; _a < 4; ++_a)                        \
        _Pragma("unroll") for (int _b = 0; _b < 4; ++_b)                    \
            (BUF)[4 * tm + _a][4 * tn + _b] = acc[_a][_b];                  \
    __syncthreads();                                                        \
    const int _tr = tid >> 4, _tc = tid & 15;                               \
    _Pragma("unroll") for (int _p = 0; _p < 4; ++_p) {                      \
      const int _il = _p * 16 + _tr;                                        \
      ushort4 _o;                                                           \
      _o.x = f2bf((BUF)[4 * _tc + 0][_il]);                                 \
      _o.y = f2bf((BUF)[4 * _tc + 1][_il]);                                 \
      _o.z = f2bf((BUF)[4 * _tc + 2][_il]);                                 \
      _o.w = f2bf((BUF)[4 * _tc + 3][_il]);                                 \
      *(ushort4*)(Mbf + (size_t)((C0) + _il) * KDIM + (R0) + 4 * _tc) = _o; \
    }                                                                       \
  }

// ---------------------------------------------------------------------------
// comb01: NOW INCLUDES the diagonal inversions (prep_inv merged in).
// Phase 0: each block inverts its superblock's four 64x64 unit-lower-tri
// diagonal blocks of (I - A), 4 wave-parallel 64-thread inversions, writing
// MT (all 4 sibling blocks write identical values - benign) and the Mbf
// mirror (gated to one block/superblock). After __syncthreads, the verified
// round-3/4 comb01 body re-reads the diagonals from MT (own-block global
// writes are visible to the block after a barrier).
// ---------------------------------------------------------------------------
__global__ __launch_bounds__(256) void comb01(const float* __restrict__ A,
                                              float* __restrict__ MT,
                                              unsigned short* __restrict__ Mbf) {
  int b = blockIdx.x;
  const int rt = b & 1;
  const int jt = (b >> 1) & 1;
  const int s = b >> 2;
  const int base = s * 256;

  __shared__ float shpool[6 * 64 * 68];
  float (*Ls)[68] = (float(*)[68])(shpool);
  float (*Rs)[68] = (float(*)[68])(shpool + 4352);
  float (*tQ0L)[68] = (float(*)[68])(shpool + 2 * 4352);
  float (*tQ0H)[68] = (float(*)[68])(shpool + 3 * 4352);
  float (*tP0)[68] = (float(*)[68])(shpool + 4 * 4352);
  float (*tP1)[68] = (float(*)[68])(shpool + 5 * 4352);
  float* As4 = shpool + 2 * 4352;  // 16384 floats, aliases tQ0L..tP1

  const int tid = threadIdx.x;
  const int k4 = tid & 15;
  const int rw = tid >> 4;
  const int tm = tid >> 4;
  const int tn = tid & 15;
  float acc[4][4];

  // ---- phase 0: invert the 4 diagonal blocks of this superblock ----
  {
    const int g = tid >> 6;  // wave id 0..3 -> diagonal 4s+g
    const int c = tid & 63;
    const int dbase = base + g * 64;
    float* Asg = As4 + g * 4096;
    for (int r = 0; r < 64; ++r)
      Asg[r * 64 + c] = A[(size_t)(dbase + r) * KDIM + dbase + c];
    __syncthreads();
    float m[64];
#pragma unroll
    for (int r = 0; r < 64; ++r) m[r] = (r == c) ? 1.f : 0.f;
#pragma unroll
    for (int r = 1; r < 64; ++r) {
      float a0 = 0.f, a1 = 0.f;
#pragma unroll
      for (int i = 0; i < 64; ++i) {
        if (i >= r) break;
        if (i & 1) a1 += Asg[r * 64 + i] * m[i];
        else       a0 += Asg[r * 64 + i] * m[i];
      }
      const float v = a0 + a1;
      m[r] = (r > c) ? v : m[r];
    }
#pragma unroll
    for (int r = 0; r < 64; r += 4)
      *(float4*)(MT + (size_t)(dbase + c) * KDIM + dbase + r) =
          make_float4(m[r], m[r + 1], m[r + 2], m[r + 3]);
    if (jt == 0 && rt == 0) {
#pragma unroll
      for (int r = 0; r < 64; ++r)
        Mbf[(size_t)(dbase + r) * KDIM + dbase + c] = f2bf(m[r]);
    }
    __syncthreads();
  }

  // ---- verified comb01 body (round 3/4) ----
  if (jt == 0) {
    STAGE_T(Ls, MT, base, base, KDIM);
    STAGE_T(Rs, A, base + 64, base, KDIM);
    __syncthreads();
    ZERO_ACC;
    mac64(Ls, Rs, tm, tn, acc);
    __syncthreads();
#pragma unroll
    for (int a = 0; a < 4; ++a)
#pragma unroll
      for (int b2 = 0; b2 < 4; ++b2) tP0[4 * tn + b2][4 * tm + a] = acc[a][b2];
    STAGE_D(Rs, MT, base + 64, base + 64, KDIM);
    __syncthreads();
    ZERO_ACC;
    mac64(tP0, Rs, tm, tn, acc);
    __syncthreads();
#pragma unroll
    for (int a = 0; a < 4; ++a)
#pragma unroll
      for (int b2 = 0; b2 < 4; ++b2) tQ0L[4 * tn + b2][4 * tm + a] = acc[a][b2];
    if (rt == 0) {
      STORE_MT(base, base + 64);
      MBF_TILE(base, base + 64, Rs);
    }
  }
  __syncthreads();

  if (rt == 1) {
    STAGE_T(Ls, MT, base + 128, base + 128, KDIM);
    STAGE_T(Rs, A, base + 192, base + 128, KDIM);
    __syncthreads();
    ZERO_ACC;
    mac64(Ls, Rs, tm, tn, acc);
    __syncthreads();
#pragma unroll
    for (int a = 0; a < 4; ++a)
#pragma unroll
      for (int b2 = 0; b2 < 4; ++b2) tP1[4 * tn + b2][4 * tm + a] = acc[a][b2];
    STAGE_D(Rs, MT, base + 192, base + 192, KDIM);
    __syncthreads();
    ZERO_ACC;
    mac64(tP1, Rs, tm, tn, acc);
    __syncthreads();
#pragma unroll
    for (int a = 0; a < 4; ++a)
#pragma unroll
      for (int b2 = 0; b2 < 4; ++b2) tQ0H[4 * tm + a][4 * tn + b2] = acc[a][b2];
    if (jt == 1) {
      STORE_MT(base + 128, base + 192);
      MBF_TILE(base + 128, base + 192, Rs);
    }
  }
  __syncthreads();

  STAGE_T(Ls, MT, base + 64 * jt, base + 64 * jt, KDIM);
  __syncthreads();
  for (int kb2 = 0; kb2 <= rt; ++kb2) {
    ZERO_ACC;
    for (int kb = jt; kb < 2; ++kb) {
      STAGE_T(Rs, A, base + 128 + 64 * kb2, base + 64 * kb, KDIM);
      __syncthreads();
      mac64(kb == jt ? Ls : tQ0L, Rs, tm, tn, acc);
      __syncthreads();
    }
    if (kb2 == 0) {
#pragma unroll
      for (int a = 0; a < 4; ++a)
#pragma unroll
        for (int b2 = 0; b2 < 4; ++b2) tP0[4 * tn + b2][4 * tm + a] = acc[a][b2];
    } else {
#pragma unroll
      for (int a = 0; a < 4; ++a)
#pragma unroll
        for (int b2 = 0; b2 < 4; ++b2) tP1[4 * tn + b2][4 * tm + a] = acc[a][b2];
    }
  }
  __syncthreads();

  ZERO_ACC;
  if (rt == 0) {
    STAGE_D(Rs, MT, base + 128, base + 128, KDIM);
    __syncthreads();
    mac64(tP0, Rs, tm, tn, acc);
    __syncthreads();
  } else {
    mac64(tP0, tQ0H, tm, tn, acc);
    __syncthreads();
    STAGE_D(Rs, MT, base + 192, base + 192, KDIM);
    __syncthreads();
    mac64(tP1, Rs, tm, tn, acc);
    __syncthreads();
  }
  STORE_MT(base + 64 * jt, base + 128 + 64 * rt);
  MBF_TILE(base + 64 * jt, base + 128 + 64 * rt, Rs);
}

// ---------------------------------------------------------------------------
// p4_stream (round-4 verified): blocks 0..31 = lv2 P tiles (64-wide);
// blocks 32+ = streaming (MT strict-lower zero, Mbf strict-upper zero,
// Z -> bf16).
// ---------------------------------------------------------------------------
__global__ __launch_bounds__(256) void p4_stream(
    const float* __restrict__ A, float* __restrict__ MT,
    float* __restrict__ Pt, const float* __restrict__ Z,
    unsigned short* __restrict__ Zbf, unsigned short* __restrict__ Mbf,
    int do_zbf) {
  __shared__ float Ls[64][68];
  __shared__ float Rs[64][68];

  if (blockIdx.x >= 32) {
    const int wid = blockIdx.x - 32;
    const int nw = gridDim.x - 32;
    const int idx0 = wid * 256 + threadIdx.x;
    const int stride = nw * 256;
    const float4 z4 = make_float4(0.f, 0.f, 0.f, 0.f);
    const uint4 u4 = make_uint4(0u, 0u, 0u, 0u);

    for (int i = idx0; i < 256 * 1024; i += stride) {
      const int blk = i >> 10, off = i & 1023;
      const int bi = blk >> 4, bj = blk & 15;
      if (bi <= bj) continue;  // strict-lower MT blocks only
      *(float4*)(MT + (size_t)(bi * 64 + (off >> 4)) * KDIM + bj * 64 +
                 4 * (off & 15)) = z4;
    }
    for (int i = idx0; i < 256 * 512; i += stride) {
      const int blk = i >> 9, off = i & 511;
      const int bi = blk >> 4, bj = blk & 15;
      if (bi >= bj) continue;  // strict-upper Mbf blocks only
      *(uint4*)(Mbf + (size_t)(bi * 64 + (off >> 3)) * KDIM + bj * 64 +
                8 * (off & 7)) = u4;
    }
    if (do_zbf) {
      for (int i = idx0; i < BDIM * KDIM / 4; i += stride) {
        float4 v = *(const float4*)(Z + 4 * (size_t)i);
        ushort4 o;
        o.x = f2bf(v.x);
        o.y = f2bf(v.y);
        o.z = f2bf(v.z);
        o.w = f2bf(v.w);
        *(ushort4*)(Zbf + 4 * (size_t)i) = o;
      }
    }
    return;
  }

  // ---- lv2 P tiles (T=4, 64-wide) ----
  int b = blockIdx.x;
  const int T = 4;
  const int rb = b % T; b /= T;
  const int jb = b % T; b /= T;
  const int c = b;
  const int h = 64 * T;
  const int base = c * 2 * h;

  const int tid = threadIdx.x;
  const int k4 = tid & 15;
  const int rw = tid >> 4;
  const int tm = tid >> 4;
  const int tn = tid & 15;
  float acc[4][4];
  ZERO_ACC;

  for (int kb = jb; kb < T; ++kb) {
    STAGE_T(Ls, MT, base + 64 * jb, base + 64 * kb, KDIM);
    STAGE_T(Rs, A, base + h + 64 * rb, base + 64 * kb, KDIM);
    __syncthreads();
    mac64(Ls, Rs, tm, tn, acc);
    __syncthreads();
  }

  float* P0 = Pt + (size_t)c * h * h;
#pragma unroll
  for (int a = 0; a < 4; ++a)
    *(float4*)(P0 + (size_t)(64 * jb + 4 * tm + a) * h + 64 * rb + 4 * tn) =
        make_float4(acc[a][0], acc[a][1], acc[a][2], acc[a][3]);
}

// ---------------------------------------------------------------------------
// p_k<T> / q_k<T>: round-4 verified 64-wide lv2/lv3 kernels.
// ---------------------------------------------------------------------------
template <int T>
__global__ __launch_bounds__(256) void p_k(const float* __restrict__ A,
                                           const float* __restrict__ MT,
                                           float* __restrict__ Pt) {
  int b = blockIdx.x;
  const int rb = b % T; b /= T;
  const int jb = b % T; b /= T;
  const int c = b;
  const int h = 64 * T;
  const int base = c * 2 * h;

  __shared__ float Ls[64][68];
  __shared__ float Rs[64][68];
  const int tid = threadIdx.x;
  const int k4 = tid & 15;
  const int rw = tid >> 4;
  const int tm = tid >> 4;
  const int tn = tid & 15;
  float acc[4][4];
  ZERO_ACC;

  for (int kb = jb; kb < T; ++kb) {
    STAGE_T(Ls, MT, base + 64 * jb, base + 64 * kb, KDIM);
    STAGE_T(Rs, A, base + h + 64 * rb, base + 64 * kb, KDIM);
    __syncthreads();
    mac64(Ls, Rs, tm, tn, acc);
    __syncthreads();
  }

  float* P0 = Pt + (size_t)c * h * h;
#pragma unroll
  for (int a = 0; a < 4; ++a)
    *(float4*)(P0 + (size_t)(64 * jb + 4 * tm + a) * h + 64 * rb + 4 * tn) =
        make_float4(acc[a][0], acc[a][1], acc[a][2], acc[a][3]);
}

template <int T>
__global__ __launch_bounds__(256) void q_k(float* __restrict__ MT,
                                           const float* __restrict__ Pt,
                                           unsigned short* __restrict__ Mbf) {
  int b = blockIdx.x;
  const int rb = b % T; b /= T;
  const int jb = b % T; b /= T;
  const int c = b;
  const int h = 64 * T;
  const int base = c * 2 * h;

  __shared__ float Ls[64][68];
  __shared__ float Rs[64][68];
  const int tid = threadIdx.x;
  const int k4 = tid & 15;
  const int rw = tid >> 4;
  const int tm = tid >> 4;
  const int tn = tid & 15;
  float acc[4][4];
  ZERO_ACC;

  const float* P0 = Pt + (size_t)c * h * h;
  for (int kb = 0; kb <= rb; ++kb) {
    STAGE_T(Ls, P0, 64 * jb, 64 * kb, h);
    STAGE_D(Rs, MT, base + h + 64 * kb, base + h + 64 * rb, KDIM);
    __syncthreads();
    mac64(Ls, Rs, tm, tn, acc);
    __syncthreads();
  }

  STORE_MT(base + 64 * jb, base + h + 64 * rb);
  MBF_TILE(base + 64 * jb, base + h + 64 * rb, Ls);
}

// ---------------------------------------------------------------------------
// bf16 MFMA GEMM with fused per-sample correction (round-4 verified),
// B-stage now via global_load_lds into a linear [128][64] Bs with
// both-sides XOR swizzle (source chunk ^= row&7; read byte ^= (row&7)<<4).
// ---------------------------------------------------------------------------
#define LDB 72

template <int ZBF>
__global__ __launch_bounds__(256) void gemm_mfma(
    const float* __restrict__ Z, const unsigned short* __restrict__ Zbf,
    const unsigned short* __restrict__ Mbf, const float* __restrict__ MT,
    const int* __restrict__ tgt, const int* __restrict__ var,
    const float* __restrict__ means, const float* __restrict__ lsc,
    float* __restrict__ C) {
  __shared__ unsigned short As[128][LDB];
#if HAS_GLL
  __shared__ unsigned short Bs[128][64];
#else
  __shared__ unsigned short Bs[128][LDB];
#endif
  __shared__ float scoef[128];
  __shared__ int stb[128];

  const int d = blockIdx.x;
  const int xbl = d & 7;
  const int nir = (d >> 3) & 7;
  const int xbh = d >> 6;
  const int xb = xbh * 8 + xbl;
  const int ni = (xb & 32) ? (7 - nir) : nir;
  const int b0 = xb * 128;
  const int i0 = ni * 128;

  const int tid = threadIdx.x;
  const int w = tid >> 6;
  const int lane = tid & 63;
  const int wr = w >> 1, wc = w & 1;
  const int mlane = lane & 15;
  const int q = lane >> 4;

  const int rq = tid >> 4, kq = tid & 15;
  const int cb = tid >> 3, ck = tid & 7;

  f32x4 acc[4][4];
#pragma unroll
  for (int a = 0; a < 4; ++a)
#pragma unroll
    for (int b = 0; b < 4; ++b) acc[a][b] = (f32x4){0.f, 0.f, 0.f, 0.f};

  const int nkb = 2 * (ni + 1);
  for (int kb = 0; kb < nkb; ++kb) {
    const int k0 = kb * 64;
    if (ZBF) {
#pragma unroll
      for (int p = 0; p < 4; ++p) {
        const int r = p * 32 + cb;
        *(uint4*)&As[r][8 * ck] =
            *(const uint4*)(Zbf + (size_t)(b0 + r) * KDIM + k0 + 8 * ck);
      }
    } else {
#pragma unroll
      for (int p = 0; p < 8; ++p) {
        const int r = p * 16 + rq;
        float4 zv = *(const float4*)(Z + (size_t)(b0 + r) * KDIM + k0 + 4 * kq);
        ushort4 o;
        o.x = f2bf(zv.x);
        o.y = f2bf(zv.y);
        o.z = f2bf(zv.z);
        o.w = f2bf(zv.w);
        *(ushort4*)&As[r][4 * kq] = o;
      }
    }
#if HAS_GLL
    {
      // wave w stages Bs rows [w*32, w*32+32): 4 DMA instrs x 8 rows.
      // lane l covers row +l>>3, 16B chunk l&7; source chunk pre-swizzled.
      const int rl = lane >> 3;
      const int ch = lane & 7;
#pragma unroll
      for (int i = 0; i < 4; ++i) {
        const int row = w * 32 + i * 8 + rl;
        const int sch = ch ^ (row & 7);
        const unsigned short* src =
            Mbf + (size_t)(i0 + row) * KDIM + k0 + sch * 8;
        __builtin_amdgcn_global_load_lds(
            (const __attribute__((address_space(1))) void*)src,
            (__attribute__((address_space(3))) void*)&Bs[w * 32 + i * 8][0],
            16, 0, 0);
      }
    }
#else
#pragma unroll
    for (int p = 0; p < 4; ++p) {
      const int c = p * 32 + cb;
      *(uint4*)&Bs[c][8 * ck] =
          *(const uint4*)(Mbf + (size_t)(i0 + c) * KDIM + k0 + 8 * ck);
    }
#endif
    __syncthreads();
#pragma unroll
    for (int ks = 0; ks < 2; ++ks) {
      const int kf = ks * 32 + q * 8;
      short8 av[4], bv[4];
#pragma unroll
      for (int a = 0; a < 4; ++a)
        av[a] = *(const short8*)&As[wr * 64 + 16 * a + mlane][kf];
#if HAS_GLL
      const char* BsB = (const char*)&Bs[0][0];
#pragma unroll
      for (int b = 0; b < 4; ++b) {
        const int row = wc * 64 + 16 * b + mlane;
        bv[b] = *(const short8*)(BsB + row * 128 +
                                 ((2 * kf) ^ ((row & 7) << 4)));
      }
#else
#pragma unroll
      for (int b = 0; b < 4; ++b)
        bv[b] = *(const short8*)&Bs[wc * 64 + 16 * b + mlane][kf];
#endif
#pragma unroll
      for (int a = 0; a < 4; ++a)
#pragma unroll
        for (int b = 0; b < 4; ++b)
          acc[a][b] =
              __builtin_amdgcn_mfma_f32_16x16x32_bf16(av[a], bv[b], acc[a][b], 0, 0, 0);
    }
    __syncthreads();
  }

  // ---- fused correction: coef for this block's 128 samples ----
  {
    const int s = tid >> 1, h2 = tid & 1;  // 2 threads per sample
    const int br = b0 + s;
    const int tb = tgt[br];
    float part = 0.f;
    if (tb >= 0) {
      const int nk16 = (tb >> 4) + 1;
      if (ZBF) {
        const unsigned short* zr = Zbf + (size_t)br * KDIM;
        const unsigned short* mr = Mbf + (size_t)tb * KDIM;
        for (int c16 = h2; c16 < nk16; c16 += 2) {
          const uint4 za = *(const uint4*)(zr + c16 * 16);
          const uint4 zb2 = *(const uint4*)(zr + c16 * 16 + 8);
          const uint4 ma = *(const uint4*)(mr + c16 * 16);
          const uint4 mb2 = *(const uint4*)(mr + c16 * 16 + 8);
          const unsigned zw[8] = {za.x, za.y, za.z, za.w,
                                  zb2.x, zb2.y, zb2.z, zb2.w};
          const unsigned mw[8] = {ma.x, ma.y, ma.z, ma.w,
                                  mb2.x, mb2.y, mb2.z, mb2.w};
#pragma unroll
          for (int wv = 0; wv < 8; ++wv) {
            part += __builtin_bit_cast(float, zw[wv] << 16) *
                    __builtin_bit_cast(float, mw[wv] << 16);
            part += __builtin_bit_cast(float, zw[wv] & 0xFFFF0000u) *
                    __builtin_bit_cast(float, mw[wv] & 0xFFFF0000u);
          }
        }
      } else {
        const float* zr = Z + (size_t)br * KDIM;
        const unsigned short* mr = Mbf + (size_t)tb * KDIM;
        const int nk8 = (tb >> 3) + 1;
        for (int c8 = h2; c8 < nk8; c8 += 2) {
          const float4 z0 = *(const float4*)(zr + c8 * 8);
          const float4 z1 = *(const float4*)(zr + c8 * 8 + 4);
          const ushort4 m0 = *(const ushort4*)(mr + c8 * 8);
          const ushort4 m1 = *(const ushort4*)(mr + c8 * 8 + 4);
          part += z0.x * bf2f(m0.x) + z0.y * bf2f(m0.y) + z0.z * bf2f(m0.z) +
                  z0.w * bf2f(m0.w) + z1.x * bf2f(m1.x) + z1.y * bf2f(m1.y) +
                  z1.z * bf2f(m1.z) + z1.w * bf2f(m1.w);
        }
      }
    }
    part += __shfl_down(part, 1);
    if (h2 == 0) {
      float cf = 0.f;
      int tbs = 0;
      if (tb >= 0) {
        const int v = var[br];
        const float mval = means[tb * VDIM + v];
        const float sval = expf(lsc[tb * VDIM + v]);
        const float zv = Z[(size_t)br * KDIM + tb];
        cf = (mval + sval * zv) - part;
        tbs = tb;
      }
      scoef[s] = cf;
      stb[s] = tbs;
    }
  }
  __syncthreads();

#pragma unroll
  for (int a = 0; a < 4; ++a) {
    const int l0 = wr * 64 + 16 * a + q * 4;
    const int row0 = b0 + l0;
#pragma unroll
    for (int b = 0; b < 4; ++b) {
      const int col = i0 + wc * 64 + 16 * b + mlane;
      float* Cp = C + (size_t)row0 * KDIM + col;
#pragma unroll
      for (int j = 0; j < 4; ++j) {
        const float cf = scoef[l0 + j];
        const float corr = cf * MT[(size_t)stb[l0 + j] * KDIM + col];
        Cp[j * KDIM] = acc[a][b][j] + corr;
      }
    }
  }
}

// ---------------------------------------------------------------------------
extern "C" void kernel_launch(void* const* d_in, const int* in_sizes, int n_in,
                              void* d_out, int out_size, void* d_ws,
                              size_t ws_size, hipStream_t stream) {
  const float* z = (const float*)d_in[0];
  const int* tgt = (const int*)d_in[1];
  const int* var = (const int*)d_in[2];
  const float* A = (const float*)d_in[3];
  const float* means = (const float*)d_in[4];
  const float* lsc = (const float*)d_in[5];
  float* out = (float*)d_out;

  char* ws = (char*)d_ws;
  float* MT = (float*)ws;                                    // 4 MB
  unsigned short* Mbf = (unsigned short*)(ws + (4u << 20));  // 2 MB
  float* Pt2 = (float*)(ws + (6u << 20));                    // 0.5 MB
  float* Pt3 = (float*)(ws + (6u << 20) + (512u << 10));     // 1 MB
  unsigned short* Zbf = (unsigned short*)(ws + (7u << 20) + (512u << 10));
  const int use_zbf =
      ws_size >= (7u << 20) + (512u << 10) + (size_t)BDIM * KDIM * 2 ? 1 : 0;

  hipLaunchKernelGGL(comb01, dim3(16), dim3(256), 0, stream, A, MT, Mbf);
  hipLaunchKernelGGL(p4_stream, dim3(512), dim3(256), 0, stream, A, MT, Pt2, z,
                     Zbf, Mbf, use_zbf);
  hipLaunchKernelGGL((q_k<4>), dim3(32), dim3(256), 0, stream, MT, Pt2, Mbf);
  hipLaunchKernelGGL((p_k<8>), dim3(64), dim3(256), 0, stream, A, MT, Pt3);
  hipLaunchKernelGGL((q_k<8>), dim3(64), dim3(256), 0, stream, MT, Pt3, Mbf);
  if (use_zbf)
    hipLaunchKernelGGL((gemm_mfma<1>), dim3((BDIM / 128) * (KDIM / 128)),
                       dim3(256), 0, stream, z, Zbf, Mbf, MT, tgt, var, means,
                       lsc, out);
  else
    hipLaunchKernelGGL((gemm_mfma<0>), dim3((BDIM / 128) * (KDIM / 128)),
                       dim3(256), 0, stream, z, Zbf, Mbf, MT, tgt, var, means,
                       lsc, out);
}